// Round 16
// baseline (145.865 us; speedup 1.0000x reference)
//
#include <hip/hip_runtime.h>

#define HIN 192
#define WOUT 384
#define NIN 32
#define NOUT 16
#define NSLOT 9
#define HP 194
#define HPLANE (HP * HP)                   // positions per plane (37636)
#define HQBATCH ((size_t)HPLANE * 18)      // uint4 elems per batch (18 quad-planes)

typedef float v2f __attribute__((ext_vector_type(2)));

__device__ __forceinline__ unsigned short f2bf(float f) {
    union { float f; unsigned int u; } v; v.f = f;
    unsigned int r = v.u + 0x7fffu + ((v.u >> 16) & 1u);   // RNE
    return (unsigned short)(r >> 16);
}
// lo: exact bf16 (shift). hi: RAW dword as f32 (bf16 + junk tail <= 2^-7 relative).
__device__ __forceinline__ v2f up2(unsigned u) {
    v2f r;
    r.x = __uint_as_float(u << 16);
    r.y = __uint_as_float(u);
    return r;
}

// ---- prep: Wt[c*256 + i*8 + j] = W[o][i][s],  m=c*8+j, s=m>>4, o=m&15 ----
__global__ __launch_bounds__(256) void kprep_w(const float* __restrict__ w, float* __restrict__ Wt) {
    int t = blockIdx.x * 256 + threadIdx.x;
    if (t >= NIN * NSLOT * NOUT) return;   // 4608
    int c = t >> 8, r = t & 255;
    int i = r >> 3, j = r & 7;
    int m = c * 8 + j;
    int s = m >> 4, o = m & 15;
    Wt[t] = w[(o * NIN + i) * NSLOT + s];
}

// ---- zero the 1-px halo border of every quad-plane ----
__global__ __launch_bounds__(256) void kzero(uint4* __restrict__ hq, int nb) {
    int t = blockIdx.x * 256 + threadIdx.x;
    if (t >= nb * 772) return;
    int b = t / 772, r = t % 772;
    int iy, ix;
    if (r < 194)      { iy = 0;           ix = r; }
    else if (r < 388) { iy = 193;         ix = r - 194; }
    else if (r < 580) { iy = r - 388 + 1; ix = 0; }
    else              { iy = r - 580 + 1; ix = 193; }
    uint4* p = hq + (size_t)b * HQBATCH + iy * HP + ix;
    uint4 z; z.x = 0; z.y = 0; z.z = 0; z.w = 0;
    #pragma unroll
    for (int c = 0; c < 18; ++c) p[(size_t)c * HPLANE] = z;
}

// ---- kA: channel mix at input resolution -> quad-plane bf16 pairs ----
__global__ __launch_bounds__(256) void kA(const float* __restrict__ x,
                                          const float* __restrict__ Wt,
                                          uint4* __restrict__ hq, int n0) {
    const int b = blockIdx.y;
    const int n = n0 + b;
    const int px = blockIdx.x * 256 + threadIdx.x;   // 0..36863
    const int iy = px / HIN, ix = px % HIN;
    const float* xp = x + (size_t)n * NIN * HIN * HIN + px;
    float xv[NIN];
    #pragma unroll
    for (int i = 0; i < NIN; ++i) xv[i] = xp[(size_t)i * HIN * HIN];
    const int pos = (iy + 1) * HP + (ix + 1);
    uint4* hb = hq + (size_t)b * HQBATCH;
    #pragma unroll 1
    for (int c = 0; c < 18; ++c) {
        const float* wc = Wt + c * 256;              // uniform -> scalar loads
        float a[8];
        #pragma unroll
        for (int j = 0; j < 8; ++j) a[j] = 0.0f;
        #pragma unroll
        for (int i = 0; i < NIN; ++i) {
            const float xi = xv[i];
            #pragma unroll
            for (int j = 0; j < 8; ++j) a[j] = fmaf(wc[i * 8 + j], xi, a[j]);
        }
        uint4 v;
        v.x = (unsigned)f2bf(a[0]) | ((unsigned)f2bf(a[1]) << 16);
        v.y = (unsigned)f2bf(a[2]) | ((unsigned)f2bf(a[3]) << 16);
        v.z = (unsigned)f2bf(a[4]) | ((unsigned)f2bf(a[5]) << 16);
        v.w = (unsigned)f2bf(a[6]) | ((unsigned)f2bf(a[7]) << 16);
        hb[(size_t)c * HPLANE + pos] = v;
    }
}

// ---- angle state from alpha for one output pixel ----
__device__ __forceinline__ void angles(const float* __restrict__ alpha, int n, int oy, int ox,
                                       float (&cc)[3], float (&ss)[3], float& rr) {
    const int aoff = (n * WOUT + oy) * WOUT + ox;
    const float a0 = alpha[aoff];
    const float a1 = alpha[(size_t)8 * WOUT * WOUT + aoff];
    rr = sqrtf(a0 * a0 + a1 * a1);
    const float inv = 1.0f / (rr + 1e-8f);
    cc[0] = a0 * inv;                      ss[0] = a1 * inv;
    cc[1] = cc[0] * cc[0] - ss[0] * ss[0]; ss[1] = 2.0f * cc[0] * ss[0];
    cc[2] = cc[1] * cc[0] - ss[1] * ss[0]; ss[2] = ss[1] * cc[0] + cc[1] * ss[0];
}

__device__ __forceinline__ float ebv(const float2 C, int s,
                                     const float (&cc)[3], const float (&ss)[3]) {
    if (s < 3) return C.x;
    if (s < 5) return C.x * cc[0] + C.y * ss[0];
    if (s < 7) return C.x * cc[1] + C.y * ss[1];
    return C.x * cc[2] + C.y * ss[2];
}

// ---- kB body: one thread = one site, ALL 4 parity pixels, 8 channels (HF half) ----
// stage row index = sbase + py (sbase = 2*ysub, wave-uniform).
template<int HF>
__device__ __forceinline__ void kb_quad(const uint4* __restrict__ hb,
                                        const float* __restrict__ alpha,
                                        const float* __restrict__ bias_,
                                        float (&stage)[4][16][128],
                                        const float2 (&Cb)[NSLOT][25],
                                        int n, int Y, int X, int lane, int sbase) {
    float cc[4][3], ss[4][3], rr[4];
    #pragma unroll
    for (int p = 0; p < 4; ++p)
        angles(alpha, n, 2 * Y + (p >> 1), 2 * X + (p & 1), cc[p], ss[p], rr[p]);

    v2f acc[4][4];
    #pragma unroll
    for (int p = 0; p < 4; ++p)
        #pragma unroll
        for (int j = 0; j < 4; ++j) { acc[p][j].x = 0.0f; acc[p][j].y = 0.0f; }

    #pragma unroll 1
    for (int ty = 0; ty < 3; ++ty) {
        const int piy = Y + 2 - ty;
        const bool tyok = (ty < 2);
        #pragma unroll 1
        for (int tx = 0; tx < 3; ++tx) {
            const bool txok = (tx < 2);
            const unsigned pos = (unsigned)(piy * HP + (X + 2 - tx));
            const int b00 = (2 * ty) * 5 + (2 * tx);          // p0 basis idx
            if (tyok && txok) {
                #pragma unroll
                for (int s = 0; s < NSLOT; ++s) {
                    const uint4 v = hb[(size_t)(2 * s + HF) * HPLANE + pos];
                    const v2f h0 = up2(v.x), h1 = up2(v.y), h2 = up2(v.z), h3 = up2(v.w);
                    const float e0 = ebv(Cb[s][b00],     s, cc[0], ss[0]);
                    const float e1 = ebv(Cb[s][b00 + 1], s, cc[1], ss[1]);
                    const float e2 = ebv(Cb[s][b00 + 5], s, cc[2], ss[2]);
                    const float e3 = ebv(Cb[s][b00 + 6], s, cc[3], ss[3]);
                    v2f e;
                    e.x = e0; e.y = e0;
                    acc[0][0] += e * h0; acc[0][1] += e * h1; acc[0][2] += e * h2; acc[0][3] += e * h3;
                    e.x = e1; e.y = e1;
                    acc[1][0] += e * h0; acc[1][1] += e * h1; acc[1][2] += e * h2; acc[1][3] += e * h3;
                    e.x = e2; e.y = e2;
                    acc[2][0] += e * h0; acc[2][1] += e * h1; acc[2][2] += e * h2; acc[2][3] += e * h3;
                    e.x = e3; e.y = e3;
                    acc[3][0] += e * h0; acc[3][1] += e * h1; acc[3][2] += e * h2; acc[3][3] += e * h3;
                }
            } else if (tyok) {          // tx==2 -> p0, p2
                #pragma unroll
                for (int s = 0; s < NSLOT; ++s) {
                    const uint4 v = hb[(size_t)(2 * s + HF) * HPLANE + pos];
                    const v2f h0 = up2(v.x), h1 = up2(v.y), h2 = up2(v.z), h3 = up2(v.w);
                    const float e0 = ebv(Cb[s][b00],     s, cc[0], ss[0]);
                    const float e2 = ebv(Cb[s][b00 + 5], s, cc[2], ss[2]);
                    v2f e;
                    e.x = e0; e.y = e0;
                    acc[0][0] += e * h0; acc[0][1] += e * h1; acc[0][2] += e * h2; acc[0][3] += e * h3;
                    e.x = e2; e.y = e2;
                    acc[2][0] += e * h0; acc[2][1] += e * h1; acc[2][2] += e * h2; acc[2][3] += e * h3;
                }
            } else if (txok) {          // ty==2 -> p0, p1
                #pragma unroll
                for (int s = 0; s < NSLOT; ++s) {
                    const uint4 v = hb[(size_t)(2 * s + HF) * HPLANE + pos];
                    const v2f h0 = up2(v.x), h1 = up2(v.y), h2 = up2(v.z), h3 = up2(v.w);
                    const float e0 = ebv(Cb[s][b00],     s, cc[0], ss[0]);
                    const float e1 = ebv(Cb[s][b00 + 1], s, cc[1], ss[1]);
                    v2f e;
                    e.x = e0; e.y = e0;
                    acc[0][0] += e * h0; acc[0][1] += e * h1; acc[0][2] += e * h2; acc[0][3] += e * h3;
                    e.x = e1; e.y = e1;
                    acc[1][0] += e * h0; acc[1][1] += e * h1; acc[1][2] += e * h2; acc[1][3] += e * h3;
                }
            } else {                    // (2,2) -> p0 only
                #pragma unroll
                for (int s = 0; s < NSLOT; ++s) {
                    const uint4 v = hb[(size_t)(2 * s + HF) * HPLANE + pos];
                    const float e0 = ebv(Cb[s][b00], s, cc[0], ss[0]);
                    v2f e; e.x = e0; e.y = e0;
                    acc[0][0] += e * up2(v.x); acc[0][1] += e * up2(v.y);
                    acc[0][2] += e * up2(v.z); acc[0][3] += e * up2(v.w);
                }
            }
        }
    }

    #pragma unroll
    for (int p = 0; p < 4; ++p) {
        const int py = p >> 1, px = p & 1;
        #pragma unroll
        for (int j = 0; j < 4; ++j) {
            stage[sbase + py][HF * 8 + 2 * j + 0][2 * lane + px] = rr[p] * acc[p][j].x + bias_[HF * 8 + 2 * j + 0];
            stage[sbase + py][HF * 8 + 2 * j + 1][2 * lane + px] = rr[p] * acc[p][j].y + bias_[HF * 8 + 2 * j + 1];
        }
    }
}

__global__ __launch_bounds__(256, 4) void kB(const uint4* __restrict__ hq,
                                             const float* __restrict__ alpha,
                                             const float* __restrict__ bias,
                                             float* __restrict__ out, int n0, int nb) {
    __shared__ float2 Cb[NSLOT][25];
    __shared__ float stage[4][16][128];   // [2*ysub+py][o][col]
    {
        const int q = threadIdx.x;
        if (q < NSLOT * 25) {
            int s = q / 25, p = q % 25;
            int ky = p / 5, kx = p % 5;
            float ys = (float)(ky - 2), xs = (float)(kx - 2);
            float r = sqrtf(xs * xs + ys * ys);
            float th = atan2f(ys, xs);
            float cr, ci;
            if (s < 3) {
                float d = r - (float)s;
                cr = expf(-d * d * (1.0f / 0.72f));
                ci = 0.0f;
            } else {
                int k = (s - 3) / 2 + 1;
                float r0 = ((s - 3) & 1) ? 2.0f : 1.0f;
                float d = r - r0;
                float ring = expf(-d * d * (1.0f / 0.72f));
                float a = (float)k * th;
                cr = ring * cosf(a);
                ci = ring * sinf(a);
            }
            Cb[s][p] = make_float2(cr, ci);
        }
    }
    __syncthreads();

    // ---- bijective XCD swizzle, Y-fastest; total = 288*nb (divisible by 8) ----
    const int tot = gridDim.x;
    const int cpx = tot >> 3;
    const int swz = ((int)blockIdx.x & 7) * cpx + ((int)blockIdx.x >> 3);
    const int Yblk = swz % 96;
    const int rest = swz / 96;
    const int b = rest % nb;
    const int bx = rest / nb;

    const int n = n0 + b;
    const int lane = threadIdx.x & 63;
    const int wv = threadIdx.x >> 6;        // 0..3 = (ysub, HF)
    const int HFv = wv & 1;
    const int ysub = wv >> 1;
    const int X0 = bx * 64;
    const int X = X0 + lane;
    const int Y = 2 * Yblk + ysub;
    const uint4* hb = hq + (size_t)b * HQBATCH;

    if (HFv == 0) kb_quad<0>(hb, alpha, bias, stage, Cb, n, Y, X, lane, 2 * ysub);
    else          kb_quad<1>(hb, alpha, bias, stage, Cb, n, Y, X, lane, 2 * ysub);

    __syncthreads();

    // cooperative coalesced store: 4 oy-rows x 16 channels x 128 px (8192 floats)
    #pragma unroll
    for (int q = 0; q < 32; ++q) {
        const int f = q * 256 + threadIdx.x;
        const int row = f >> 7, col = f & 127;  // row 0..63
        const int d = row >> 4, o = row & 15;   // d = 2*ysub+py
        out[(((size_t)n * NOUT + o) * WOUT + (4 * Yblk + d)) * WOUT + 2 * X0 + col]
            = stage[d][o][col];
    }
}

// ---- fallback: proven round-1 monolithic kernel ----
__global__ __launch_bounds__(256) void steered_convT(
    const float* __restrict__ x, const float* __restrict__ alpha,
    const float* __restrict__ weights, const float* __restrict__ bias,
    float* __restrict__ out) {
    __shared__ float sb[15 * 25];
    for (int q = threadIdx.x; q < 375; q += 256) {
        int s = q / 25, p = q % 25;
        int ky = p / 5, kx = p % 5;
        float ys = (float)(ky - 2), xs = (float)(kx - 2);
        float r = sqrtf(xs * xs + ys * ys);
        float th = atan2f(ys, xs);
        float val;
        if (s < 3) { float d = r - (float)s; val = expf(-d * d * (1.0f / 0.72f)); }
        else {
            int k = (s - 3) / 4 + 1; int rem = (s - 3) & 3;
            float r0 = (rem & 1) ? 2.0f : 1.0f; float d = r - r0;
            float ring = expf(-d * d * (1.0f / 0.72f));
            float ang = (float)k * th;
            val = ring * ((rem < 2) ? cosf(ang) : sinf(ang));
        }
        sb[q] = val;
    }
    __syncthreads();
    int idx = blockIdx.x * 256 + threadIdx.x;
    int ox = idx % WOUT; int tt = idx / WOUT; int oy = tt % WOUT; int n = tt / WOUT;
    const int plane = WOUT * WOUT;
    int aoff = (n * WOUT + oy) * WOUT + ox;
    float a0 = alpha[aoff], a1 = alpha[8 * plane + aoff];
    float rho = sqrtf(a0 * a0 + a1 * a1);
    float inv = 1.0f / (rho + 1e-8f);
    float c1 = a0 * inv, s1 = a1 * inv;
    float c2 = c1 * c1 - s1 * s1, s2 = 2.0f * s1 * c1;
    float c3 = c2 * c1 - s2 * s1, s3 = s2 * c1 + c2 * s1;
    int py = oy & 1, px = ox & 1;
    int iy0 = (oy >> 1) + 1, ix0 = (ox >> 1) + 1;
    float eb[9][9]; int off[9];
    #pragma unroll
    for (int t = 0; t < 9; ++t) {
        int ty = t / 3, tx = t % 3;
        int ky = py + 2 * ty, kx = px + 2 * tx;
        int iy = iy0 - ty, ix = ix0 - tx;
        bool v = (ky < 5) && (kx < 5) && (iy >= 0) && (iy < HIN) && (ix >= 0) && (ix < HIN);
        float m = v ? 1.0f : 0.0f;
        int ciy = min(max(iy, 0), HIN - 1), cix = min(max(ix, 0), HIN - 1);
        off[t] = ciy * HIN + cix;
        int bi_ = min(ky, 4) * 5 + min(kx, 4);
        eb[0][t] = sb[0 * 25 + bi_] * m;
        eb[1][t] = sb[1 * 25 + bi_] * m;
        eb[2][t] = sb[2 * 25 + bi_] * m;
        eb[3][t] = (sb[3 * 25 + bi_] * c1 + sb[5 * 25 + bi_] * s1) * m;
        eb[4][t] = (sb[4 * 25 + bi_] * c1 + sb[6 * 25 + bi_] * s1) * m;
        eb[5][t] = (sb[7 * 25 + bi_] * c2 + sb[9 * 25 + bi_] * s2) * m;
        eb[6][t] = (sb[8 * 25 + bi_] * c2 + sb[10 * 25 + bi_] * s2) * m;
        eb[7][t] = (sb[11 * 25 + bi_] * c3 + sb[13 * 25 + bi_] * s3) * m;
        eb[8][t] = (sb[12 * 25 + bi_] * c3 + sb[14 * 25 + bi_] * s3) * m;
    }
    float acc[NOUT];
    #pragma unroll
    for (int o = 0; o < NOUT; ++o) acc[o] = 0.0f;
    const float* xn = x + (size_t)n * NIN * HIN * HIN;
    for (int i = 0; i < NIN; ++i) {
        const float* xp = xn + (size_t)i * HIN * HIN;
        float tap[9];
        #pragma unroll
        for (int t = 0; t < 9; ++t) tap[t] = xp[off[t]];
        float G[9];
        #pragma unroll
        for (int b = 0; b < 9; ++b) {
            float s = 0.0f;
            #pragma unroll
            for (int t = 0; t < 9; ++t) s += eb[b][t] * tap[t];
            G[b] = s;
        }
        const float* wp = weights + i * 9;
        #pragma unroll
        for (int o = 0; o < NOUT; ++o) {
            float s = acc[o];
            #pragma unroll
            for (int b = 0; b < 9; ++b) s += wp[o * NIN * 9 + b] * G[b];
            acc[o] = s;
        }
    }
    #pragma unroll
    for (int o = 0; o < NOUT; ++o)
        out[((size_t)(n * NOUT + o) * WOUT + oy) * WOUT + ox] = rho * acc[o] + bias[o];
}

extern "C" void kernel_launch(void* const* d_in, const int* in_sizes, int n_in,
                              void* d_out, int out_size, void* d_ws, size_t ws_size,
                              hipStream_t stream) {
    const float* x       = (const float*)d_in[0];
    const float* alpha   = (const float*)d_in[1];
    const float* weights = (const float*)d_in[2];
    const float* bias    = (const float*)d_in[3];
    float* out = (float*)d_out;

    const size_t hoff = 32768;
    const size_t perb = HQBATCH * 16;        // bytes per batch of h
    int cb = 0;
    if (ws_size > hoff) cb = (int)((ws_size - hoff) / perb);
    if (cb > 8) cb = 8;

    if (cb < 1) {
        const int pixels = 8 * WOUT * WOUT;
        steered_convT<<<dim3(pixels / 256), 256, 0, stream>>>(x, alpha, weights, bias, out);
        return;
    }

    float* Wt = (float*)d_ws;
    uint4* hq = (uint4*)((char*)d_ws + hoff);

    kprep_w<<<dim3(18), 256, 0, stream>>>(weights, Wt);

    for (int n0 = 0; n0 < 8; n0 += cb) {
        int nb = 8 - n0; if (nb > cb) nb = cb;
        kzero<<<dim3((nb * 772 + 255) / 256), 256, 0, stream>>>(hq, nb);
        kA<<<dim3(144, nb), 256, 0, stream>>>(x, Wt, hq, n0);
        kB<<<dim3(288 * nb), 256, 0, stream>>>(hq, alpha, bias, out, n0, nb);
    }
}

// Round 17
// 143.193 us; speedup vs baseline: 1.0187x; 1.0187x over previous
//
#include <hip/hip_runtime.h>

#define HIN 192
#define WOUT 384
#define NIN 32
#define NOUT 16
#define NSLOT 9
#define HP 194
#define HPLANE (HP * HP)                   // positions per plane (37636)
#define HQBATCH ((size_t)HPLANE * 18)      // uint4 elems per batch (18 quad-planes)

typedef float v2f __attribute__((ext_vector_type(2)));

__device__ __forceinline__ unsigned short f2bf(float f) {
    union { float f; unsigned int u; } v; v.f = f;
    unsigned int r = v.u + 0x7fffu + ((v.u >> 16) & 1u);   // RNE
    return (unsigned short)(r >> 16);
}
// lo: exact bf16 (shift). hi: RAW dword as f32 (bf16 + junk tail <= 2^-7 relative).
__device__ __forceinline__ v2f up2(unsigned u) {
    v2f r;
    r.x = __uint_as_float(u << 16);
    r.y = __uint_as_float(u);
    return r;
}

// ---- prep: Wt[c*256 + i*8 + j] = W[o][i][s],  m=c*8+j, s=m>>4, o=m&15 ----
__global__ __launch_bounds__(256) void kprep_w(const float* __restrict__ w, float* __restrict__ Wt) {
    int t = blockIdx.x * 256 + threadIdx.x;
    if (t >= NIN * NSLOT * NOUT) return;   // 4608
    int c = t >> 8, r = t & 255;
    int i = r >> 3, j = r & 7;
    int m = c * 8 + j;
    int s = m >> 4, o = m & 15;
    Wt[t] = w[(o * NIN + i) * NSLOT + s];
}

// ---- zero the 1-px halo border of every quad-plane ----
__global__ __launch_bounds__(256) void kzero(uint4* __restrict__ hq, int nb) {
    int t = blockIdx.x * 256 + threadIdx.x;
    if (t >= nb * 772) return;
    int b = t / 772, r = t % 772;
    int iy, ix;
    if (r < 194)      { iy = 0;           ix = r; }
    else if (r < 388) { iy = 193;         ix = r - 194; }
    else if (r < 580) { iy = r - 388 + 1; ix = 0; }
    else              { iy = r - 580 + 1; ix = 193; }
    uint4* p = hq + (size_t)b * HQBATCH + iy * HP + ix;
    uint4 z; z.x = 0; z.y = 0; z.z = 0; z.w = 0;
    #pragma unroll
    for (int c = 0; c < 18; ++c) p[(size_t)c * HPLANE] = z;
}

// ---- kA: channel mix at input resolution -> quad-plane bf16 pairs ----
__global__ __launch_bounds__(256) void kA(const float* __restrict__ x,
                                          const float* __restrict__ Wt,
                                          uint4* __restrict__ hq, int n0) {
    const int b = blockIdx.y;
    const int n = n0 + b;
    const int px = blockIdx.x * 256 + threadIdx.x;   // 0..36863
    const int iy = px / HIN, ix = px % HIN;
    const float* xp = x + (size_t)n * NIN * HIN * HIN + px;
    float xv[NIN];
    #pragma unroll
    for (int i = 0; i < NIN; ++i) xv[i] = xp[(size_t)i * HIN * HIN];
    const int pos = (iy + 1) * HP + (ix + 1);
    uint4* hb = hq + (size_t)b * HQBATCH;
    #pragma unroll 1
    for (int c = 0; c < 18; ++c) {
        const float* wc = Wt + c * 256;              // uniform -> scalar loads
        float a[8];
        #pragma unroll
        for (int j = 0; j < 8; ++j) a[j] = 0.0f;
        #pragma unroll
        for (int i = 0; i < NIN; ++i) {
            const float xi = xv[i];
            #pragma unroll
            for (int j = 0; j < 8; ++j) a[j] = fmaf(wc[i * 8 + j], xi, a[j]);
        }
        uint4 v;
        v.x = (unsigned)f2bf(a[0]) | ((unsigned)f2bf(a[1]) << 16);
        v.y = (unsigned)f2bf(a[2]) | ((unsigned)f2bf(a[3]) << 16);
        v.z = (unsigned)f2bf(a[4]) | ((unsigned)f2bf(a[5]) << 16);
        v.w = (unsigned)f2bf(a[6]) | ((unsigned)f2bf(a[7]) << 16);
        hb[(size_t)c * HPLANE + pos] = v;
    }
}

// ---- angle state from alpha for one output pixel ----
__device__ __forceinline__ void angles(const float* __restrict__ alpha, int n, int oy, int ox,
                                       float (&cc)[3], float (&ss)[3], float& rr) {
    const int aoff = (n * WOUT + oy) * WOUT + ox;
    const float a0 = alpha[aoff];
    const float a1 = alpha[(size_t)8 * WOUT * WOUT + aoff];
    rr = sqrtf(a0 * a0 + a1 * a1);
    const float inv = 1.0f / (rr + 1e-8f);
    cc[0] = a0 * inv;                      ss[0] = a1 * inv;
    cc[1] = cc[0] * cc[0] - ss[0] * ss[0]; ss[1] = 2.0f * cc[0] * ss[0];
    cc[2] = cc[1] * cc[0] - ss[1] * ss[0]; ss[2] = ss[1] * cc[0] + cc[1] * ss[0];
}

__device__ __forceinline__ float ebv(const float2 C, int s,
                                     const float (&cc)[3], const float (&ss)[3]) {
    // s is a compile-time constant at each unrolled call site
    if (s < 3) return C.x;
    if (s < 5) return C.x * cc[0] + C.y * ss[0];
    if (s < 7) return C.x * cc[1] + C.y * ss[1];
    return C.x * cc[2] + C.y * ss[2];
}

// ---- kB body: one wave = (pair, half); one thread = one site, 2 parity pixels, 8 ch ----
// PAIR 0: A=(0,0) all 9 taps, B=(1,1) taps ty<2&&tx<2.
// PAIR 1: A=(0,1) taps tx<2,   B=(1,0) taps ty<2.
// Direct stride-2 stores (no LDS stage): complementary parity waves fill the
// other half of each line; L2 write-combining merges before HBM.
template<int PAIR, int HF>
__device__ __forceinline__ void kb_pair(const uint4* __restrict__ hb,
                                        const float* __restrict__ alpha,
                                        const float* __restrict__ bias_,
                                        float* __restrict__ out,
                                        const float2 (&Cb)[NSLOT][25],
                                        int n, int Y, int X) {
    constexpr int AX = (PAIR == 0) ? 0 : 1;   // A = (PY=0, AX)
    constexpr int BX = (PAIR == 0) ? 1 : 0;   // B = (PY=1, BX)

    float ccA[3], ssA[3], ccB[3], ssB[3], rrA, rrB;
    angles(alpha, n, 2 * Y + 0, 2 * X + AX, ccA, ssA, rrA);
    angles(alpha, n, 2 * Y + 1, 2 * X + BX, ccB, ssB, rrB);

    v2f aA[4], aB[4];
    #pragma unroll
    for (int j = 0; j < 4; ++j) { aA[j].x = 0.0f; aA[j].y = 0.0f; aB[j].x = 0.0f; aB[j].y = 0.0f; }

    #pragma unroll 1
    for (int ty = 0; ty < 3; ++ty) {
        const int piy = Y + 2 - ty;
        #pragma unroll 1
        for (int tx = 0; tx < 3; ++tx) {
            const bool useA = (tx < 3 - AX);                 // A: PY=0 -> ty always valid
            const bool useB = (ty < 2) && (tx < 3 - BX);
            if (!useA && !useB) continue;                    // pair1 (2,2) only
            const int pix = X + 2 - tx;
            const unsigned pos = (unsigned)(piy * HP + pix);
            const int biA = (0 + 2 * ty) * 5 + (AX + 2 * tx);
            const int biB = (1 + 2 * ty) * 5 + (BX + 2 * tx);
            if (useA && useB) {
                #pragma unroll
                for (int s = 0; s < NSLOT; ++s) {
                    const uint4 v = hb[(size_t)(2 * s + HF) * HPLANE + pos];
                    const float eA = ebv(Cb[s][biA], s, ccA, ssA);
                    const float eB = ebv(Cb[s][biB], s, ccB, ssB);
                    v2f eA2; eA2.x = eA; eA2.y = eA;
                    v2f eB2; eB2.x = eB; eB2.y = eB;
                    v2f h0 = up2(v.x), h1 = up2(v.y), h2 = up2(v.z), h3 = up2(v.w);
                    aA[0] += eA2 * h0; aA[1] += eA2 * h1; aA[2] += eA2 * h2; aA[3] += eA2 * h3;
                    aB[0] += eB2 * h0; aB[1] += eB2 * h1; aB[2] += eB2 * h2; aB[3] += eB2 * h3;
                }
            } else if (useA) {
                #pragma unroll
                for (int s = 0; s < NSLOT; ++s) {
                    const uint4 v = hb[(size_t)(2 * s + HF) * HPLANE + pos];
                    const float eA = ebv(Cb[s][biA], s, ccA, ssA);
                    v2f eA2; eA2.x = eA; eA2.y = eA;
                    aA[0] += eA2 * up2(v.x); aA[1] += eA2 * up2(v.y);
                    aA[2] += eA2 * up2(v.z); aA[3] += eA2 * up2(v.w);
                }
            } else {
                #pragma unroll
                for (int s = 0; s < NSLOT; ++s) {
                    const uint4 v = hb[(size_t)(2 * s + HF) * HPLANE + pos];
                    const float eB = ebv(Cb[s][biB], s, ccB, ssB);
                    v2f eB2; eB2.x = eB; eB2.y = eB;
                    aB[0] += eB2 * up2(v.x); aB[1] += eB2 * up2(v.y);
                    aB[2] += eB2 * up2(v.z); aB[3] += eB2 * up2(v.w);
                }
            }
        }
    }

    // direct stores: rows oy=2Y (A, x offset AX) and oy=2Y+1 (B, x offset BX)
    const size_t rowA = (((size_t)n * NOUT + HF * 8) * WOUT + (2 * Y + 0)) * WOUT + 2 * X + AX;
    const size_t rowB = (((size_t)n * NOUT + HF * 8) * WOUT + (2 * Y + 1)) * WOUT + 2 * X + BX;
    #pragma unroll
    for (int j = 0; j < 4; ++j) {
        const float b0 = bias_[HF * 8 + 2 * j + 0];
        const float b1 = bias_[HF * 8 + 2 * j + 1];
        out[rowA + (size_t)(2 * j + 0) * WOUT * WOUT] = rrA * aA[j].x + b0;
        out[rowA + (size_t)(2 * j + 1) * WOUT * WOUT] = rrA * aA[j].y + b1;
        out[rowB + (size_t)(2 * j + 0) * WOUT * WOUT] = rrB * aB[j].x + b0;
        out[rowB + (size_t)(2 * j + 1) * WOUT * WOUT] = rrB * aB[j].y + b1;
    }
}

__global__ __launch_bounds__(256, 4) void kB(const uint4* __restrict__ hq,
                                             const float* __restrict__ alpha,
                                             const float* __restrict__ bias,
                                             float* __restrict__ out, int n0, int nb) {
    __shared__ float2 Cb[NSLOT][25];
    {
        const int q = threadIdx.x;
        if (q < NSLOT * 25) {
            int s = q / 25, p = q % 25;
            int ky = p / 5, kx = p % 5;
            float ys = (float)(ky - 2), xs = (float)(kx - 2);
            float r = sqrtf(xs * xs + ys * ys);
            float th = atan2f(ys, xs);
            float cr, ci;
            if (s < 3) {
                float d = r - (float)s;
                cr = expf(-d * d * (1.0f / 0.72f));
                ci = 0.0f;
            } else {
                int k = (s - 3) / 2 + 1;
                float r0 = ((s - 3) & 1) ? 2.0f : 1.0f;
                float d = r - r0;
                float ring = expf(-d * d * (1.0f / 0.72f));
                float a = (float)k * th;
                cr = ring * cosf(a);
                ci = ring * sinf(a);
            }
            Cb[s][p] = make_float2(cr, ci);
        }
    }
    __syncthreads();

    // ---- bijective XCD swizzle, Y-fastest; total = 576*nb (divisible by 8) ----
    const int tot = gridDim.x;
    const int cpx = tot >> 3;
    const int swz = ((int)blockIdx.x & 7) * cpx + ((int)blockIdx.x >> 3);
    const int Y = swz % 192;
    const int rest = swz / 192;
    const int b = rest % nb;
    const int bx = rest / nb;

    const int n = n0 + b;
    const int lane = threadIdx.x & 63;
    const int wv = threadIdx.x >> 6;        // 0..3 = (HF, pair)
    const int X = bx * 64 + lane;
    const uint4* hb = hq + (size_t)b * HQBATCH;

    switch (wv) {
        case 0: kb_pair<0, 0>(hb, alpha, bias, out, Cb, n, Y, X); break;
        case 1: kb_pair<1, 0>(hb, alpha, bias, out, Cb, n, Y, X); break;
        case 2: kb_pair<0, 1>(hb, alpha, bias, out, Cb, n, Y, X); break;
        default: kb_pair<1, 1>(hb, alpha, bias, out, Cb, n, Y, X); break;
    }
}

// ---- fallback: proven round-1 monolithic kernel ----
__global__ __launch_bounds__(256) void steered_convT(
    const float* __restrict__ x, const float* __restrict__ alpha,
    const float* __restrict__ weights, const float* __restrict__ bias,
    float* __restrict__ out) {
    __shared__ float sb[15 * 25];
    for (int q = threadIdx.x; q < 375; q += 256) {
        int s = q / 25, p = q % 25;
        int ky = p / 5, kx = p % 5;
        float ys = (float)(ky - 2), xs = (float)(kx - 2);
        float r = sqrtf(xs * xs + ys * ys);
        float th = atan2f(ys, xs);
        float val;
        if (s < 3) { float d = r - (float)s; val = expf(-d * d * (1.0f / 0.72f)); }
        else {
            int k = (s - 3) / 4 + 1; int rem = (s - 3) & 3;
            float r0 = (rem & 1) ? 2.0f : 1.0f; float d = r - r0;
            float ring = expf(-d * d * (1.0f / 0.72f));
            float ang = (float)k * th;
            val = ring * ((rem < 2) ? cosf(ang) : sinf(ang));
        }
        sb[q] = val;
    }
    __syncthreads();
    int idx = blockIdx.x * 256 + threadIdx.x;
    int ox = idx % WOUT; int tt = idx / WOUT; int oy = tt % WOUT; int n = tt / WOUT;
    const int plane = WOUT * WOUT;
    int aoff = (n * WOUT + oy) * WOUT + ox;
    float a0 = alpha[aoff], a1 = alpha[8 * plane + aoff];
    float rho = sqrtf(a0 * a0 + a1 * a1);
    float inv = 1.0f / (rho + 1e-8f);
    float c1 = a0 * inv, s1 = a1 * inv;
    float c2 = c1 * c1 - s1 * s1, s2 = 2.0f * s1 * c1;
    float c3 = c2 * c1 - s2 * s1, s3 = s2 * c1 + c2 * s1;
    int py = oy & 1, px = ox & 1;
    int iy0 = (oy >> 1) + 1, ix0 = (ox >> 1) + 1;
    float eb[9][9]; int off[9];
    #pragma unroll
    for (int t = 0; t < 9; ++t) {
        int ty = t / 3, tx = t % 3;
        int ky = py + 2 * ty, kx = px + 2 * tx;
        int iy = iy0 - ty, ix = ix0 - tx;
        bool v = (ky < 5) && (kx < 5) && (iy >= 0) && (iy < HIN) && (ix >= 0) && (ix < HIN);
        float m = v ? 1.0f : 0.0f;
        int ciy = min(max(iy, 0), HIN - 1), cix = min(max(ix, 0), HIN - 1);
        off[t] = ciy * HIN + cix;
        int bi_ = min(ky, 4) * 5 + min(kx, 4);
        eb[0][t] = sb[0 * 25 + bi_] * m;
        eb[1][t] = sb[1 * 25 + bi_] * m;
        eb[2][t] = sb[2 * 25 + bi_] * m;
        eb[3][t] = (sb[3 * 25 + bi_] * c1 + sb[5 * 25 + bi_] * s1) * m;
        eb[4][t] = (sb[4 * 25 + bi_] * c1 + sb[6 * 25 + bi_] * s1) * m;
        eb[5][t] = (sb[7 * 25 + bi_] * c2 + sb[9 * 25 + bi_] * s2) * m;
        eb[6][t] = (sb[8 * 25 + bi_] * c2 + sb[10 * 25 + bi_] * s2) * m;
        eb[7][t] = (sb[11 * 25 + bi_] * c3 + sb[13 * 25 + bi_] * s3) * m;
        eb[8][t] = (sb[12 * 25 + bi_] * c3 + sb[14 * 25 + bi_] * s3) * m;
    }
    float acc[NOUT];
    #pragma unroll
    for (int o = 0; o < NOUT; ++o) acc[o] = 0.0f;
    const float* xn = x + (size_t)n * NIN * HIN * HIN;
    for (int i = 0; i < NIN; ++i) {
        const float* xp = xn + (size_t)i * HIN * HIN;
        float tap[9];
        #pragma unroll
        for (int t = 0; t < 9; ++t) tap[t] = xp[off[t]];
        float G[9];
        #pragma unroll
        for (int b = 0; b < 9; ++b) {
            float s = 0.0f;
            #pragma unroll
            for (int t = 0; t < 9; ++t) s += eb[b][t] * tap[t];
            G[b] = s;
        }
        const float* wp = weights + i * 9;
        #pragma unroll
        for (int o = 0; o < NOUT; ++o) {
            float s = acc[o];
            #pragma unroll
            for (int b = 0; b < 9; ++b) s += wp[o * NIN * 9 + b] * G[b];
            acc[o] = s;
        }
    }
    #pragma unroll
    for (int o = 0; o < NOUT; ++o)
        out[((size_t)(n * NOUT + o) * WOUT + oy) * WOUT + ox] = rho * acc[o] + bias[o];
}

extern "C" void kernel_launch(void* const* d_in, const int* in_sizes, int n_in,
                              void* d_out, int out_size, void* d_ws, size_t ws_size,
                              hipStream_t stream) {
    const float* x       = (const float*)d_in[0];
    const float* alpha   = (const float*)d_in[1];
    const float* weights = (const float*)d_in[2];
    const float* bias    = (const float*)d_in[3];
    float* out = (float*)d_out;

    const size_t hoff = 32768;
    const size_t perb = HQBATCH * 16;        // bytes per batch of h
    int cb = 0;
    if (ws_size > hoff) cb = (int)((ws_size - hoff) / perb);
    if (cb > 8) cb = 8;

    if (cb < 1) {
        const int pixels = 8 * WOUT * WOUT;
        steered_convT<<<dim3(pixels / 256), 256, 0, stream>>>(x, alpha, weights, bias, out);
        return;
    }

    float* Wt = (float*)d_ws;
    uint4* hq = (uint4*)((char*)d_ws + hoff);

    kprep_w<<<dim3(18), 256, 0, stream>>>(weights, Wt);

    for (int n0 = 0; n0 < 8; n0 += cb) {
        int nb = 8 - n0; if (nb > cb) nb = cb;
        kzero<<<dim3((nb * 772 + 255) / 256), 256, 0, stream>>>(hq, nb);
        kA<<<dim3(144, nb), 256, 0, stream>>>(x, Wt, hq, n0);
        kB<<<dim3(576 * nb), 256, 0, stream>>>(hq, alpha, bias, out, n0, nb);
    }
}

// Round 18
// 139.343 us; speedup vs baseline: 1.0468x; 1.0276x over previous
//
#include <hip/hip_runtime.h>

#define HIN 192
#define WOUT 384
#define NIN 32
#define NOUT 16
#define NSLOT 9
#define HP 194
#define HPLANE (HP * HP)                   // positions per plane (37636)
#define HQBATCH ((size_t)HPLANE * 18)      // uint4 elems per batch (18 quad-planes)

typedef float v2f __attribute__((ext_vector_type(2)));

__device__ __forceinline__ unsigned short f2bf(float f) {
    union { float f; unsigned int u; } v; v.f = f;
    unsigned int r = v.u + 0x7fffu + ((v.u >> 16) & 1u);   // RNE
    return (unsigned short)(r >> 16);
}
// lo: exact bf16 (shift). hi: RAW dword as f32 (bf16 + junk tail <= 2^-7 relative).
__device__ __forceinline__ v2f up2(unsigned u) {
    v2f r;
    r.x = __uint_as_float(u << 16);
    r.y = __uint_as_float(u);
    return r;
}

// ---- prep: Wt[c*256 + i*8 + j] = W[o][i][s],  m=c*8+j, s=m>>4, o=m&15 ----
__global__ __launch_bounds__(256) void kprep_w(const float* __restrict__ w, float* __restrict__ Wt) {
    int t = blockIdx.x * 256 + threadIdx.x;
    if (t >= NIN * NSLOT * NOUT) return;   // 4608
    int c = t >> 8, r = t & 255;
    int i = r >> 3, j = r & 7;
    int m = c * 8 + j;
    int s = m >> 4, o = m & 15;
    Wt[t] = w[(o * NIN + i) * NSLOT + s];
}

// ---- zero the 1-px halo border of every quad-plane ----
__global__ __launch_bounds__(256) void kzero(uint4* __restrict__ hq, int nb) {
    int t = blockIdx.x * 256 + threadIdx.x;
    if (t >= nb * 772) return;
    int b = t / 772, r = t % 772;
    int iy, ix;
    if (r < 194)      { iy = 0;           ix = r; }
    else if (r < 388) { iy = 193;         ix = r - 194; }
    else if (r < 580) { iy = r - 388 + 1; ix = 0; }
    else              { iy = r - 580 + 1; ix = 193; }
    uint4* p = hq + (size_t)b * HQBATCH + iy * HP + ix;
    uint4 z; z.x = 0; z.y = 0; z.z = 0; z.w = 0;
    #pragma unroll
    for (int c = 0; c < 18; ++c) p[(size_t)c * HPLANE] = z;
}

// ---- kA: channel mix at input resolution -> quad-plane bf16 pairs ----
__global__ __launch_bounds__(256) void kA(const float* __restrict__ x,
                                          const float* __restrict__ Wt,
                                          uint4* __restrict__ hq, int n0) {
    const int b = blockIdx.y;
    const int n = n0 + b;
    const int px = blockIdx.x * 256 + threadIdx.x;   // 0..36863
    const int iy = px / HIN, ix = px % HIN;
    const float* xp = x + (size_t)n * NIN * HIN * HIN + px;
    float xv[NIN];
    #pragma unroll
    for (int i = 0; i < NIN; ++i) xv[i] = xp[(size_t)i * HIN * HIN];
    const int pos = (iy + 1) * HP + (ix + 1);
    uint4* hb = hq + (size_t)b * HQBATCH;
    #pragma unroll 1
    for (int c = 0; c < 18; ++c) {
        const float* wc = Wt + c * 256;              // uniform -> scalar loads
        float a[8];
        #pragma unroll
        for (int j = 0; j < 8; ++j) a[j] = 0.0f;
        #pragma unroll
        for (int i = 0; i < NIN; ++i) {
            const float xi = xv[i];
            #pragma unroll
            for (int j = 0; j < 8; ++j) a[j] = fmaf(wc[i * 8 + j], xi, a[j]);
        }
        uint4 v;
        v.x = (unsigned)f2bf(a[0]) | ((unsigned)f2bf(a[1]) << 16);
        v.y = (unsigned)f2bf(a[2]) | ((unsigned)f2bf(a[3]) << 16);
        v.z = (unsigned)f2bf(a[4]) | ((unsigned)f2bf(a[5]) << 16);
        v.w = (unsigned)f2bf(a[6]) | ((unsigned)f2bf(a[7]) << 16);
        hb[(size_t)c * HPLANE + pos] = v;
    }
}

// ---- angle state from alpha for one output pixel ----
__device__ __forceinline__ void angles(const float* __restrict__ alpha, int n, int oy, int ox,
                                       float (&cc)[3], float (&ss)[3], float& rr) {
    const int aoff = (n * WOUT + oy) * WOUT + ox;
    const float a0 = alpha[aoff];
    const float a1 = alpha[(size_t)8 * WOUT * WOUT + aoff];
    rr = sqrtf(a0 * a0 + a1 * a1);
    const float inv = 1.0f / (rr + 1e-8f);
    cc[0] = a0 * inv;                      ss[0] = a1 * inv;
    cc[1] = cc[0] * cc[0] - ss[0] * ss[0]; ss[1] = 2.0f * cc[0] * ss[0];
    cc[2] = cc[1] * cc[0] - ss[1] * ss[0]; ss[2] = ss[1] * cc[0] + cc[1] * ss[0];
}

__device__ __forceinline__ float ebv(const float2 C, int s,
                                     const float (&cc)[3], const float (&ss)[3]) {
    // s is a compile-time constant at each unrolled call site
    if (s < 3) return C.x;
    if (s < 5) return C.x * cc[0] + C.y * ss[0];
    if (s < 7) return C.x * cc[1] + C.y * ss[1];
    return C.x * cc[2] + C.y * ss[2];
}

// ---- kB body: one wave = (pair, half); one thread = one site, 2 parity pixels, 8 ch ----
// PAIR 0: A=(0,0) all 9 taps, B=(1,1) taps ty<2&&tx<2.
// PAIR 1: A=(0,1) taps tx<2,   B=(1,0) taps ty<2.
template<int PAIR, int HF>
__device__ __forceinline__ void kb_pair(const uint4* __restrict__ hb,
                                        const float* __restrict__ alpha,
                                        const float* __restrict__ bias_,
                                        float (&stage)[2][16][128],
                                        const float2 (&Cb)[NSLOT][25],
                                        int n, int Y, int X, int lane) {
    constexpr int AX = (PAIR == 0) ? 0 : 1;   // A = (PY=0, AX)
    constexpr int BX = (PAIR == 0) ? 1 : 0;   // B = (PY=1, BX)

    float ccA[3], ssA[3], ccB[3], ssB[3], rrA, rrB;
    angles(alpha, n, 2 * Y + 0, 2 * X + AX, ccA, ssA, rrA);
    angles(alpha, n, 2 * Y + 1, 2 * X + BX, ccB, ssB, rrB);

    v2f aA[4], aB[4];
    #pragma unroll
    for (int j = 0; j < 4; ++j) { aA[j].x = 0.0f; aA[j].y = 0.0f; aB[j].x = 0.0f; aB[j].y = 0.0f; }

    #pragma unroll 1
    for (int ty = 0; ty < 3; ++ty) {
        const int piy = Y + 2 - ty;
        #pragma unroll 1
        for (int tx = 0; tx < 3; ++tx) {
            const bool useA = (tx < 3 - AX);                 // A: PY=0 -> ty always valid
            const bool useB = (ty < 2) && (tx < 3 - BX);
            if (!useA && !useB) continue;                    // pair1 (2,2) only
            const int pix = X + 2 - tx;
            const unsigned pos = (unsigned)(piy * HP + pix);
            const int biA = (0 + 2 * ty) * 5 + (AX + 2 * tx);
            const int biB = (1 + 2 * ty) * 5 + (BX + 2 * tx);
            if (useA && useB) {
                #pragma unroll
                for (int s = 0; s < NSLOT; ++s) {
                    const uint4 v = hb[(size_t)(2 * s + HF) * HPLANE + pos];
                    const float eA = ebv(Cb[s][biA], s, ccA, ssA);
                    const float eB = ebv(Cb[s][biB], s, ccB, ssB);
                    v2f eA2; eA2.x = eA; eA2.y = eA;
                    v2f eB2; eB2.x = eB; eB2.y = eB;
                    v2f h0 = up2(v.x), h1 = up2(v.y), h2 = up2(v.z), h3 = up2(v.w);
                    aA[0] += eA2 * h0; aA[1] += eA2 * h1; aA[2] += eA2 * h2; aA[3] += eA2 * h3;
                    aB[0] += eB2 * h0; aB[1] += eB2 * h1; aB[2] += eB2 * h2; aB[3] += eB2 * h3;
                }
            } else if (useA) {
                #pragma unroll
                for (int s = 0; s < NSLOT; ++s) {
                    const uint4 v = hb[(size_t)(2 * s + HF) * HPLANE + pos];
                    const float eA = ebv(Cb[s][biA], s, ccA, ssA);
                    v2f eA2; eA2.x = eA; eA2.y = eA;
                    aA[0] += eA2 * up2(v.x); aA[1] += eA2 * up2(v.y);
                    aA[2] += eA2 * up2(v.z); aA[3] += eA2 * up2(v.w);
                }
            } else {
                #pragma unroll
                for (int s = 0; s < NSLOT; ++s) {
                    const uint4 v = hb[(size_t)(2 * s + HF) * HPLANE + pos];
                    const float eB = ebv(Cb[s][biB], s, ccB, ssB);
                    v2f eB2; eB2.x = eB; eB2.y = eB;
                    aB[0] += eB2 * up2(v.x); aB[1] += eB2 * up2(v.y);
                    aB[2] += eB2 * up2(v.z); aB[3] += eB2 * up2(v.w);
                }
            }
        }
    }

    #pragma unroll
    for (int j = 0; j < 4; ++j) {
        stage[0][HF * 8 + 2 * j + 0][2 * lane + AX] = rrA * aA[j].x + bias_[HF * 8 + 2 * j + 0];
        stage[0][HF * 8 + 2 * j + 1][2 * lane + AX] = rrA * aA[j].y + bias_[HF * 8 + 2 * j + 1];
        stage[1][HF * 8 + 2 * j + 0][2 * lane + BX] = rrB * aB[j].x + bias_[HF * 8 + 2 * j + 0];
        stage[1][HF * 8 + 2 * j + 1][2 * lane + BX] = rrB * aB[j].y + bias_[HF * 8 + 2 * j + 1];
    }
}

__global__ __launch_bounds__(256, 4) void kB(const uint4* __restrict__ hq,
                                             const float* __restrict__ alpha,
                                             const float* __restrict__ bias,
                                             float* __restrict__ out, int n0, int nb) {
    __shared__ float2 Cb[NSLOT][25];
    __shared__ float stage[2][16][128];
    {
        const int q = threadIdx.x;
        if (q < NSLOT * 25) {
            int s = q / 25, p = q % 25;
            int ky = p / 5, kx = p % 5;
            float ys = (float)(ky - 2), xs = (float)(kx - 2);
            float r = sqrtf(xs * xs + ys * ys);
            float th = atan2f(ys, xs);
            float cr, ci;
            if (s < 3) {
                float d = r - (float)s;
                cr = expf(-d * d * (1.0f / 0.72f));
                ci = 0.0f;
            } else {
                int k = (s - 3) / 2 + 1;
                float r0 = ((s - 3) & 1) ? 2.0f : 1.0f;
                float d = r - r0;
                float ring = expf(-d * d * (1.0f / 0.72f));
                float a = (float)k * th;
                cr = ring * cosf(a);
                ci = ring * sinf(a);
            }
            Cb[s][p] = make_float2(cr, ci);
        }
    }
    __syncthreads();

    // ---- bijective XCD swizzle, Y-fastest ----
    const int tot = gridDim.x;
    const int cpx = tot >> 3;
    const int swz = ((int)blockIdx.x & 7) * cpx + ((int)blockIdx.x >> 3);
    const int Y = swz % 192;
    const int rest = swz / 192;
    const int b = rest % nb;
    const int bx = rest / nb;

    const int n = n0 + b;
    const int lane = threadIdx.x & 63;
    const int wv = threadIdx.x >> 6;        // 0..3 = (HF, pair)
    const int X0 = bx * 64;
    const int X = X0 + lane;
    const uint4* hb = hq + (size_t)b * HQBATCH;

    switch (wv) {
        case 0: kb_pair<0, 0>(hb, alpha, bias, stage, Cb, n, Y, X, lane); break;
        case 1: kb_pair<1, 0>(hb, alpha, bias, stage, Cb, n, Y, X, lane); break;
        case 2: kb_pair<0, 1>(hb, alpha, bias, stage, Cb, n, Y, X, lane); break;
        default: kb_pair<1, 1>(hb, alpha, bias, stage, Cb, n, Y, X, lane); break;
    }

    __syncthreads();

    // cooperative coalesced store: 2 oy-rows x 16 channels x 128 px (4096 floats)
    #pragma unroll
    for (int q = 0; q < 16; ++q) {
        const int f = q * 256 + threadIdx.x;
        const int row = f >> 7, col = f & 127;
        const int py = row >> 4, o = row & 15;
        out[(((size_t)n * NOUT + o) * WOUT + (2 * Y + py)) * WOUT + 2 * X0 + col]
            = stage[py][o][col];
    }
}

// ---- fallback: proven round-1 monolithic kernel ----
__global__ __launch_bounds__(256) void steered_convT(
    const float* __restrict__ x, const float* __restrict__ alpha,
    const float* __restrict__ weights, const float* __restrict__ bias,
    float* __restrict__ out) {
    __shared__ float sb[15 * 25];
    for (int q = threadIdx.x; q < 375; q += 256) {
        int s = q / 25, p = q % 25;
        int ky = p / 5, kx = p % 5;
        float ys = (float)(ky - 2), xs = (float)(kx - 2);
        float r = sqrtf(xs * xs + ys * ys);
        float th = atan2f(ys, xs);
        float val;
        if (s < 3) { float d = r - (float)s; val = expf(-d * d * (1.0f / 0.72f)); }
        else {
            int k = (s - 3) / 4 + 1; int rem = (s - 3) & 3;
            float r0 = (rem & 1) ? 2.0f : 1.0f; float d = r - r0;
            float ring = expf(-d * d * (1.0f / 0.72f));
            float ang = (float)k * th;
            val = ring * ((rem < 2) ? cosf(ang) : sinf(ang));
        }
        sb[q] = val;
    }
    __syncthreads();
    int idx = blockIdx.x * 256 + threadIdx.x;
    int ox = idx % WOUT; int tt = idx / WOUT; int oy = tt % WOUT; int n = tt / WOUT;
    const int plane = WOUT * WOUT;
    int aoff = (n * WOUT + oy) * WOUT + ox;
    float a0 = alpha[aoff], a1 = alpha[8 * plane + aoff];
    float rho = sqrtf(a0 * a0 + a1 * a1);
    float inv = 1.0f / (rho + 1e-8f);
    float c1 = a0 * inv, s1 = a1 * inv;
    float c2 = c1 * c1 - s1 * s1, s2 = 2.0f * s1 * c1;
    float c3 = c2 * c1 - s2 * s1, s3 = s2 * c1 + c2 * s1;
    int py = oy & 1, px = ox & 1;
    int iy0 = (oy >> 1) + 1, ix0 = (ox >> 1) + 1;
    float eb[9][9]; int off[9];
    #pragma unroll
    for (int t = 0; t < 9; ++t) {
        int ty = t / 3, tx = t % 3;
        int ky = py + 2 * ty, kx = px + 2 * tx;
        int iy = iy0 - ty, ix = ix0 - tx;
        bool v = (ky < 5) && (kx < 5) && (iy >= 0) && (iy < HIN) && (ix >= 0) && (ix < HIN);
        float m = v ? 1.0f : 0.0f;
        int ciy = min(max(iy, 0), HIN - 1), cix = min(max(ix, 0), HIN - 1);
        off[t] = ciy * HIN + cix;
        int bi_ = min(ky, 4) * 5 + min(kx, 4);
        eb[0][t] = sb[0 * 25 + bi_] * m;
        eb[1][t] = sb[1 * 25 + bi_] * m;
        eb[2][t] = sb[2 * 25 + bi_] * m;
        eb[3][t] = (sb[3 * 25 + bi_] * c1 + sb[5 * 25 + bi_] * s1) * m;
        eb[4][t] = (sb[4 * 25 + bi_] * c1 + sb[6 * 25 + bi_] * s1) * m;
        eb[5][t] = (sb[7 * 25 + bi_] * c2 + sb[9 * 25 + bi_] * s2) * m;
        eb[6][t] = (sb[8 * 25 + bi_] * c2 + sb[10 * 25 + bi_] * s2) * m;
        eb[7][t] = (sb[11 * 25 + bi_] * c3 + sb[13 * 25 + bi_] * s3) * m;
        eb[8][t] = (sb[12 * 25 + bi_] * c3 + sb[14 * 25 + bi_] * s3) * m;
    }
    float acc[NOUT];
    #pragma unroll
    for (int o = 0; o < NOUT; ++o) acc[o] = 0.0f;
    const float* xn = x + (size_t)n * NIN * HIN * HIN;
    for (int i = 0; i < NIN; ++i) {
        const float* xp = xn + (size_t)i * HIN * HIN;
        float tap[9];
        #pragma unroll
        for (int t = 0; t < 9; ++t) tap[t] = xp[off[t]];
        float G[9];
        #pragma unroll
        for (int b = 0; b < 9; ++b) {
            float s = 0.0f;
            #pragma unroll
            for (int t = 0; t < 9; ++t) s += eb[b][t] * tap[t];
            G[b] = s;
        }
        const float* wp = weights + i * 9;
        #pragma unroll
        for (int o = 0; o < NOUT; ++o) {
            float s = acc[o];
            #pragma unroll
            for (int b = 0; b < 9; ++b) s += wp[o * NIN * 9 + b] * G[b];
            acc[o] = s;
        }
    }
    #pragma unroll
    for (int o = 0; o < NOUT; ++o)
        out[((size_t)(n * NOUT + o) * WOUT + oy) * WOUT + ox] = rho * acc[o] + bias[o];
}

extern "C" void kernel_launch(void* const* d_in, const int* in_sizes, int n_in,
                              void* d_out, int out_size, void* d_ws, size_t ws_size,
                              hipStream_t stream) {
    const float* x       = (const float*)d_in[0];
    const float* alpha   = (const float*)d_in[1];
    const float* weights = (const float*)d_in[2];
    const float* bias    = (const float*)d_in[3];
    float* out = (float*)d_out;

    const size_t hoff = 32768;
    const size_t perb = HQBATCH * 16;        // bytes per batch of h
    int cb = 0;
    if (ws_size > hoff) cb = (int)((ws_size - hoff) / perb);
    if (cb > 8) cb = 8;

    if (cb < 1) {
        const int pixels = 8 * WOUT * WOUT;
        steered_convT<<<dim3(pixels / 256), 256, 0, stream>>>(x, alpha, weights, bias, out);
        return;
    }

    float* Wt = (float*)d_ws;
    uint4* hq = (uint4*)((char*)d_ws + hoff);

    kprep_w<<<dim3(18), 256, 0, stream>>>(weights, Wt);

    for (int n0 = 0; n0 < 8; n0 += cb) {
        int nb = 8 - n0; if (nb > cb) nb = cb;
        kzero<<<dim3((nb * 772 + 255) / 256), 256, 0, stream>>>(hq, nb);
        kA<<<dim3(144, nb), 256, 0, stream>>>(x, Wt, hq, n0);
        kB<<<dim3(576 * nb), 256, 0, stream>>>(hq, alpha, bias, out, n0, nb);
    }
}